// Round 5
// baseline (216.910 us; speedup 1.0000x reference)
//
#include <hip/hip_runtime.h>

// Problem constants (match reference)
#define BQ 512
#define AQ 32
#define DQ 256
#define NQ (BQ * AQ)      // 16384 nodes
#define EQ 1048576        // edges
#define THR 0.5f
#define EPSF 1e-5f
#define DEG_STRIDE 160    // per-target list cap; deg ~ Binom(E,1/N) mean 64, +12 sigma
#define BIN_TGTS 64       // targets per bin
#define NBINS (NQ / BIN_TGTS)          // 256
#define BIN_STRIDE 4864   // mean 4096 edges/bin, sigma ~64, +12 sigma

typedef __attribute__((ext_vector_type(8))) short bf16x8;
typedef __attribute__((ext_vector_type(4))) float f32x4;

// fp32 -> bf16 round-to-nearest-even (finite inputs)
__device__ __forceinline__ unsigned short f2bf(float f) {
    unsigned int u = __float_as_uint(f);
    return (unsigned short)((u + 0x7FFFu + ((u >> 16) & 1u)) >> 16);
}
__device__ __forceinline__ float bf2f(unsigned short h) {
    return __uint_as_float((unsigned int)h << 16);
}

// ---------------------------------------------------------------------------
// Dispatch 1: W [K,N] fp32 -> Wt hi/lo [N,K] bf16 split; zero deg (16K ints,
// 64/block) and bin_cursor (block 0). ~4 us.
// ---------------------------------------------------------------------------
__global__ __launch_bounds__(256) void k_wt(
        const float* __restrict__ W, unsigned short* __restrict__ Wt,
        int* __restrict__ bin_cursor, int* __restrict__ deg) {
    int tid = threadIdx.x;
    int idx = blockIdx.x * 256 + tid;       // covers DQ*DQ
    int n = idx >> 8;
    int k = idx & 255;
    float w = W[k * DQ + n];
    unsigned short h = f2bf(w);
    Wt[idx] = h;                            // hi plane
    Wt[DQ * DQ + idx] = f2bf(w - bf2f(h));  // lo plane
    if (tid < 64) deg[blockIdx.x * 64 + tid] = 0;
    if (blockIdx.x == 0) bin_cursor[tid] = 0;   // tid < 256 == NBINS
}

// ---------------------------------------------------------------------------
// Dispatch 2 — heavy slices overlapped:
//  blocks [0,256):    edge partition (EXACT round-0/4 code) + fire-and-forget
//                     global deg atomics (replaces the k_cnt dispatch; 1M
//                     no-return atomics over 16K addresses, hidden under the
//                     co-resident GEMM blocks' latency).
//  blocks [256,512):  bf16x3 split MFMA GEMM (EXACT round-0/4 code).
// ---------------------------------------------------------------------------
__global__ __launch_bounds__(256) void k_part_gemm(
        const float* __restrict__ Xp, const unsigned short* __restrict__ Wt,
        unsigned short* __restrict__ xwb,
        const int* __restrict__ src, const int* __restrict__ tgt,
        int* __restrict__ bin_cursor, unsigned int* __restrict__ binned,
        int* __restrict__ deg) {
    __shared__ int hist[NBINS];
    int tid = threadIdx.x;
    if (blockIdx.x < 256) {
        // ---- edge partition ----
        hist[tid] = 0;
        __syncthreads();
        int base = blockIdx.x * 4096;
        int t[16], s[16];
        #pragma unroll
        for (int i = 0; i < 16; i++) {
            int e = base + i * 256 + tid;
            t[i] = tgt[e];
            s[i] = src[e];
            atomicAdd(&hist[t[i] >> 6], 1);
        }
        __syncthreads();
        int mine = hist[tid];
        __syncthreads();
        hist[tid] = tid * BIN_STRIDE + atomicAdd(&bin_cursor[tid], mine);
        __syncthreads();
        #pragma unroll
        for (int i = 0; i < 16; i++) {
            int slot = atomicAdd(&hist[t[i] >> 6], 1);
            binned[slot] = ((unsigned int)t[i] << 14) | (unsigned int)s[i];
        }
        // ---- global degree counts (fire-and-forget, no return value) ----
        #pragma unroll
        for (int i = 0; i < 16; i++) atomicAdd(&deg[t[i]], 1);
        return;
    }
    // ---- bf16x3 split MFMA GEMM (unchanged, verified rounds 5-13) ----
    // A frag: A[m=lane&15][k=quad*8+j]; B frag from Wt[n][k]; C/D row=quad*4+r,
    // col=lane&15.
    int wave = tid >> 6;
    int lane = tid & 63;
    int col = lane & 15;
    int quad = lane >> 4;
    int mbase = (blockIdx.x - 256) * 64 + wave * 16;
    int m = mbase + col;

    const float* arow = Xp + (size_t)m * DQ;
    const unsigned short* Wlo = Wt + DQ * DQ;

    f32x4 acc[16];
    f32x4 zero = {0.f, 0.f, 0.f, 0.f};
    #pragma unroll
    for (int i = 0; i < 16; i++) acc[i] = zero;

    for (int k0 = 0; k0 < DQ; k0 += 32) {
        int kq = k0 + quad * 8;
        float4 a0 = *(const float4*)(arow + kq);
        float4 a1 = *(const float4*)(arow + kq + 4);
        float av[8] = {a0.x, a0.y, a0.z, a0.w, a1.x, a1.y, a1.z, a1.w};
        bf16x8 ah, al;
        #pragma unroll
        for (int j = 0; j < 8; j++) {
            unsigned short h = f2bf(av[j]);
            ah[j] = (short)h;
            al[j] = (short)f2bf(av[j] - bf2f(h));
        }
        #pragma unroll
        for (int nt = 0; nt < 16; nt++) {
            size_t boff = (size_t)(nt * 16 + col) * DQ + kq;
            bf16x8 bh = *(const bf16x8*)(Wt + boff);
            bf16x8 bl = *(const bf16x8*)(Wlo + boff);
            acc[nt] = __builtin_amdgcn_mfma_f32_16x16x32_bf16(ah, bh, acc[nt], 0, 0, 0);
            acc[nt] = __builtin_amdgcn_mfma_f32_16x16x32_bf16(al, bh, acc[nt], 0, 0, 0);
            acc[nt] = __builtin_amdgcn_mfma_f32_16x16x32_bf16(ah, bl, acc[nt], 0, 0, 0);
        }
    }

    #pragma unroll
    for (int nt = 0; nt < 16; nt++) {
        #pragma unroll
        for (int r = 0; r < 4; r++) {
            xwb[(size_t)(mbase + quad * 4 + r) * DQ + nt * 16 + col] =
                f2bf(acc[nt][r]);
        }
    }
}

// ---------------------------------------------------------------------------
// Fused aggregation + scores — round-3/4 structure (512 thr, 8 waves, phase-0
// LDS scatter of this clip's half-bin) with a re-pipelined gather:
//  * cross-chunk software pipeline: chunk k+1's index read + deg[] scatter-
//    gather (the ~300cy serial head of each chunk) issues BEFORE chunk k's
//    FMA block, hiding it under 64 row-loads.
//  * row-load unroll deepened 8 -> 16 (16x512B in flight per wave).
//  * dinv computed on the fly as rsqrtf(deg+1) (round-2 proved bit-identical).
// Per-actor FP summation order unchanged (appended c=0 terms add exact 0.0).
// ---------------------------------------------------------------------------
__global__ __launch_bounds__(512) void k_agg_scores(
        const unsigned int* __restrict__ xwb,
        const unsigned int* __restrict__ binned,
        const int* __restrict__ bin_cursor,
        const int* __restrict__ deg,
        const float* __restrict__ bias,
        float* __restrict__ out,      // Xo [NQ*DQ]
        float* __restrict__ mask) {   // [BQ*AQ*AQ]
    __shared__ float xs[AQ][DQ + 4];   // 33 KB; rows 1040B = 65x16B aligned
    __shared__ float sq[AQ];
    __shared__ float sc[AQ][AQ + 1];
    __shared__ float rmin[AQ], rmax[AQ];
    __shared__ unsigned short lbuck[AQ * DEG_STRIDE];  // 10 KB
    __shared__ int lcnt[AQ];

    int tid = threadIdx.x;
    int wave = tid >> 6;              // 0..7
    int lane = tid & 63;
    int bq = blockIdx.x;              // batch clip
    const uint2* xw2 = (const uint2*)xwb;

    // ---- phase 0: scatter this clip's edges into per-actor LDS lists ----
    if (tid < AQ) lcnt[tid] = 0;
    __syncthreads();
    {
        int b = bq >> 1;              // bin covering clips {2b, 2b+1}
        int beg = b * BIN_STRIDE;
        int count = bin_cursor[b];
        if (count > BIN_STRIDE) count = BIN_STRIDE;
        for (int i = beg + tid; i < beg + count; i += 512) {
            unsigned int ed = binned[i];
            if ((int)(ed >> 19) == bq) {          // target's clip == mine
                int a = (ed >> 14) & 31;
                int pos = atomicAdd(&lcnt[a], 1);
                if (pos < DEG_STRIDE)
                    lbuck[a * DEG_STRIDE + pos] = (unsigned short)(ed & 0x3FFFu);
            }
        }
    }
    __syncthreads();

    float4 bv = ((const float4*)bias)[lane];

    // ---- phase 1: gather 4 targets per wave, chunk-pipelined ----
    #pragma unroll 1
    for (int i = 0; i < 4; i++) {
        int a = wave * 4 + i;         // actor 0..31
        int t = bq * AQ + a;
        float dt = rsqrtf((float)(deg[t] + 1));
        float c0 = dt * dt;
        uint2 sp = xw2[(size_t)t * 64 + lane];
        float4 acc;
        acc.x = __uint_as_float(sp.x << 16) * c0;
        acc.y = __uint_as_float(sp.x & 0xFFFF0000u) * c0;
        acc.z = __uint_as_float(sp.y << 16) * c0;
        acc.w = __uint_as_float(sp.y & 0xFFFF0000u) * c0;

        int num = lcnt[a];
        if (num > DEG_STRIDE) num = DEG_STRIDE;

        // prologue: chunk 0 index + coef
        int e_cur = 0, n_cur = 0;
        float cl_cur = 0.f;
        if (num > 0) {
            n_cur = num < 64 ? num : 64;
            int idx = (lane < n_cur ? lane : 0);
            e_cur = (int)lbuck[a * DEG_STRIDE + idx];
            cl_cur = (lane < n_cur) ? rsqrtf((float)(deg[e_cur] + 1)) * dt : 0.f;
        }
        #pragma unroll 1
        for (int k0 = 0; k0 < num; k0 += 64) {
            // issue next chunk's index read + deg scatter-gather early
            int k1 = k0 + 64;
            int e_nxt = 0, n_nxt = 0;
            float cl_nxt = 0.f;
            if (k1 < num) {
                n_nxt = (num - k1) < 64 ? (num - k1) : 64;
                int idx = k1 + (lane < n_nxt ? lane : 0);
                e_nxt = (int)lbuck[a * DEG_STRIDE + idx];
                cl_nxt = (lane < n_nxt) ? rsqrtf((float)(deg[e_nxt] + 1)) * dt : 0.f;
            }
            // consume current chunk: 16-deep row-load/FMA stream
            int n16 = (n_cur + 15) & ~15;     // <= 64 always
            for (int j0 = 0; j0 < n16; j0 += 16) {
                #pragma unroll
                for (int jj = 0; jj < 16; jj++) {
                    int j = j0 + jj;
                    int s = __shfl(e_cur, j);
                    float c = __shfl(cl_cur, j);
                    uint2 p = xw2[(size_t)s * 64 + lane];
                    acc.x += __uint_as_float(p.x << 16) * c;
                    acc.y += __uint_as_float(p.x & 0xFFFF0000u) * c;
                    acc.z += __uint_as_float(p.y << 16) * c;
                    acc.w += __uint_as_float(p.y & 0xFFFF0000u) * c;
                }
            }
            e_cur = e_nxt; cl_cur = cl_nxt; n_cur = n_nxt;
        }

        acc.x += bv.x; acc.y += bv.y; acc.z += bv.z; acc.w += bv.w;
        ((float4*)out)[(size_t)t * 64 + lane] = acc;
        *(float4*)&xs[a][lane * 4] = acc;
    }
    __syncthreads();

    // ---- phase 2: scores (identical math to round 0) ----
    if (tid < AQ) {
        const float4* xi = (const float4*)xs[tid];
        float s = 0.f;
        #pragma unroll 8
        for (int dd = 0; dd < DQ / 4; dd++) {
            float4 a = xi[dd];
            s += a.x * a.x + a.y * a.y + a.z * a.z + a.w * a.w;
        }
        sq[tid] = s;
    }
    __syncthreads();

    {
        int p0 = tid * 2;             // 2 pairs per thread (1024 pairs)
        int i = p0 >> 5;
        int j0 = p0 & 31;
        const float4* xi = (const float4*)xs[i];
        float g[2] = {0.f, 0.f};
        for (int dd = 0; dd < DQ / 4; dd += 8) {
            float4 ar[8];
            #pragma unroll
            for (int u = 0; u < 8; u++) ar[u] = xi[dd + u];
            #pragma unroll
            for (int q = 0; q < 2; q++) {
                const float4* xj = (const float4*)xs[j0 + q];
                float gq = 0.f;
                #pragma unroll
                for (int u = 0; u < 8; u++) {
                    float4 b = xj[dd + u];
                    gq += ar[u].x * b.x + ar[u].y * b.y +
                          ar[u].z * b.z + ar[u].w * b.w;
                }
                g[q] += gq;
            }
        }
        #pragma unroll
        for (int q = 0; q < 2; q++) {
            sc[i][j0 + q] = sq[i] - 2.f * g[q] + sq[j0 + q];
        }
    }
    __syncthreads();

    if (tid < AQ) {
        float mn = sc[tid][0], mx = sc[tid][0];
        for (int j = 1; j < AQ; j++) {
            float v = sc[tid][j];
            mn = fminf(mn, v);
            mx = fmaxf(mx, v);
        }
        rmin[tid] = mn;
        rmax[tid] = mx;
    }
    __syncthreads();

    {
        float* mb = mask + (size_t)bq * AQ * AQ;
        int p0 = tid * 2;
        int i = p0 >> 5, j0 = p0 & 31;
        float inv = 1.0f / (rmax[i] - rmin[i] + EPSF);
        float2 mv;
        mv.x = ((sc[i][j0 + 0] - rmin[i]) * inv > THR) ? 1.0f : 0.0f;
        mv.y = ((sc[i][j0 + 1] - rmin[i]) * inv > THR) ? 1.0f : 0.0f;
        ((float2*)mb)[tid] = mv;
    }
}

// ---------------------------------------------------------------------------
extern "C" void kernel_launch(void* const* d_in, const int* in_sizes, int n_in,
                              void* d_out, int out_size, void* d_ws, size_t ws_size,
                              hipStream_t stream) {
    const float* X    = (const float*)d_in[0];   // [B,A,D]
    const int*   ei   = (const int*)d_in[1];     // [2,E]
    const float* W    = (const float*)d_in[2];   // [D,D]
    const float* bias = (const float*)d_in[3];   // [D]
    float* out = (float*)d_out;                  // [N*D] Xo  ++  [B*A*A] mask

    char* ws = (char*)d_ws;
    unsigned short* xwb = (unsigned short*)ws;                              // 8 MB
    unsigned int* binned = (unsigned int*)(ws + (size_t)NQ * DQ * 2);       // 4.98 MB
    unsigned short* Wt = (unsigned short*)(binned + (size_t)NBINS * BIN_STRIDE); // 256 KB
    int* deg = (int*)(Wt + 2 * DQ * DQ);                                    // 64 KB
    int* bin_cursor = (int*)(deg + NQ);                                     // 1 KB

    const int* src = ei;
    const int* tgt = ei + EQ;

    k_wt<<<256, 256, 0, stream>>>(W, Wt, bin_cursor, deg);
    k_part_gemm<<<512, 256, 0, stream>>>(X, Wt, xwb, src, tgt, bin_cursor,
                                         binned, deg);
    k_agg_scores<<<BQ, 512, 0, stream>>>((const unsigned int*)xwb, binned,
                                         bin_cursor, deg, bias, out,
                                         out + (size_t)NQ * DQ);
}

// Round 6
// 179.141 us; speedup vs baseline: 1.2108x; 1.2108x over previous
//
#include <hip/hip_runtime.h>

// Problem constants (match reference)
#define BQ 512
#define AQ 32
#define DQ 256
#define NQ (BQ * AQ)      // 16384 nodes
#define EQ 1048576        // edges
#define THR 0.5f
#define EPSF 1e-5f
#define DEG_STRIDE 160    // per-target list cap; deg ~ Binom(E,1/N) mean 64, +12 sigma
#define BIN_TGTS 64       // targets per bin
#define NBINS (NQ / BIN_TGTS)          // 256
#define BIN_STRIDE 4864   // mean 4096 edges/bin, sigma ~64, +12 sigma

typedef __attribute__((ext_vector_type(8))) short bf16x8;
typedef __attribute__((ext_vector_type(4))) float f32x4;

// fp32 -> bf16 round-to-nearest-even (finite inputs)
__device__ __forceinline__ unsigned short f2bf(float f) {
    unsigned int u = __float_as_uint(f);
    return (unsigned short)((u + 0x7FFFu + ((u >> 16) & 1u)) >> 16);
}
__device__ __forceinline__ float bf2f(unsigned short h) {
    return __uint_as_float((unsigned int)h << 16);
}

// ---------------------------------------------------------------------------
// Dispatch 1: W [K,N] fp32 -> Wt hi/lo [N,K] bf16 split; block 0 zeroes
// bin_cursor. ~4 us.
// ---------------------------------------------------------------------------
__global__ __launch_bounds__(256) void k_wt(
        const float* __restrict__ W, unsigned short* __restrict__ Wt,
        int* __restrict__ bin_cursor) {
    int tid = threadIdx.x;
    int idx = blockIdx.x * 256 + tid;       // covers DQ*DQ
    int n = idx >> 8;
    int k = idx & 255;
    float w = W[k * DQ + n];
    unsigned short h = f2bf(w);
    Wt[idx] = h;                            // hi plane
    Wt[DQ * DQ + idx] = f2bf(w - bf2f(h));  // lo plane
    if (blockIdx.x == 0) bin_cursor[tid] = 0;   // tid < 256 == NBINS
}

// ---------------------------------------------------------------------------
// Dispatch 2: edge partition into 256 target-range bins (EXACT round-0/4
// code, now its own named dispatch for counter attribution; NO deg atomics —
// round-5 proved them a +22us regression).
// ---------------------------------------------------------------------------
__global__ __launch_bounds__(256) void k_part(
        const int* __restrict__ src, const int* __restrict__ tgt,
        int* __restrict__ bin_cursor, unsigned int* __restrict__ binned) {
    __shared__ int hist[NBINS];
    int tid = threadIdx.x;
    hist[tid] = 0;
    __syncthreads();
    int base = blockIdx.x * 4096;
    int t[16], s[16];
    #pragma unroll
    for (int i = 0; i < 16; i++) {
        int e = base + i * 256 + tid;
        t[i] = tgt[e];
        s[i] = src[e];
        atomicAdd(&hist[t[i] >> 6], 1);
    }
    __syncthreads();
    int mine = hist[tid];
    __syncthreads();
    hist[tid] = tid * BIN_STRIDE + atomicAdd(&bin_cursor[tid], mine);
    __syncthreads();
    #pragma unroll
    for (int i = 0; i < 16; i++) {
        int slot = atomicAdd(&hist[t[i] >> 6], 1);
        binned[slot] = ((unsigned int)t[i] << 14) | (unsigned int)s[i];
    }
}

// ---------------------------------------------------------------------------
// Dispatch 3: bf16x3 split MFMA GEMM with LDS-STAGED B. Same MFMA sequence
// and accumulation order as rounds 0-4 (bit-identical output); only the
// B-fragment source changes from L2 (~300cy exposed at 2 waves/SIMD) to LDS.
// Per 32-wide K-slab: stage Wt hi+lo [256n x 32k] into LDS (80B-padded rows
// -> 2-way bank aliasing = free on ds_read_b128).
// ---------------------------------------------------------------------------
__global__ __launch_bounds__(256) void k_gemm(
        const float* __restrict__ Xp, const unsigned short* __restrict__ Wt,
        unsigned short* __restrict__ xwb) {
    __shared__ unsigned short bs[2][256 * 40];   // 2 planes x 256 rows x 80B = 40 KB
    int tid = threadIdx.x;
    int wave = tid >> 6;
    int lane = tid & 63;
    int col = lane & 15;
    int quad = lane >> 4;
    int mbase = blockIdx.x * 64 + wave * 16;
    int m = mbase + col;

    const float* arow = Xp + (size_t)m * DQ;
    const unsigned short* Wlo = Wt + DQ * DQ;

    f32x4 acc[16];
    f32x4 zero = {0.f, 0.f, 0.f, 0.f};
    #pragma unroll
    for (int i = 0; i < 16; i++) acc[i] = zero;

    for (int k0 = 0; k0 < DQ; k0 += 32) {
        // ---- stage B slab: thread t loads row n=t, cols [k0,k0+32), both planes
        __syncthreads();              // previous slab fully consumed
        {
            const uint4* gh = (const uint4*)(Wt + tid * DQ + k0);   // 64B contig
            const uint4* gl = (const uint4*)(Wlo + tid * DQ + k0);
            uint4* lh = (uint4*)&bs[0][tid * 40];
            uint4* ll = (uint4*)&bs[1][tid * 40];
            #pragma unroll
            for (int u = 0; u < 4; u++) lh[u] = gh[u];
            #pragma unroll
            for (int u = 0; u < 4; u++) ll[u] = gl[u];
        }
        __syncthreads();

        int kq = k0 + quad * 8;
        float4 a0 = *(const float4*)(arow + kq);
        float4 a1 = *(const float4*)(arow + kq + 4);
        float av[8] = {a0.x, a0.y, a0.z, a0.w, a1.x, a1.y, a1.z, a1.w};
        bf16x8 ah, al;
        #pragma unroll
        for (int j = 0; j < 8; j++) {
            unsigned short h = f2bf(av[j]);
            ah[j] = (short)h;
            al[j] = (short)f2bf(av[j] - bf2f(h));
        }
        #pragma unroll
        for (int nt = 0; nt < 16; nt++) {
            int n = nt * 16 + col;
            bf16x8 bh = *(const bf16x8*)&bs[0][n * 40 + quad * 8];
            bf16x8 bl = *(const bf16x8*)&bs[1][n * 40 + quad * 8];
            acc[nt] = __builtin_amdgcn_mfma_f32_16x16x32_bf16(ah, bh, acc[nt], 0, 0, 0);
            acc[nt] = __builtin_amdgcn_mfma_f32_16x16x32_bf16(al, bh, acc[nt], 0, 0, 0);
            acc[nt] = __builtin_amdgcn_mfma_f32_16x16x32_bf16(ah, bl, acc[nt], 0, 0, 0);
        }
    }

    #pragma unroll
    for (int nt = 0; nt < 16; nt++) {
        #pragma unroll
        for (int r = 0; r < 4; r++) {
            xwb[(size_t)(mbase + quad * 4 + r) * DQ + nt * 16 + col] =
                f2bf(acc[nt][r]);
        }
    }
}

// ---------------------------------------------------------------------------
// Dispatch 4: per-bin degree count -> dinv (EXACT round-3/4 code). ~10 us.
// ---------------------------------------------------------------------------
__global__ __launch_bounds__(256) void k_cnt(
        const int* __restrict__ bin_cursor, const unsigned int* __restrict__ binned,
        float* __restrict__ dinv) {
    __shared__ int lcnt[BIN_TGTS];
    int tid = threadIdx.x;
    int b = blockIdx.x;
    if (tid < BIN_TGTS) lcnt[tid] = 0;
    __syncthreads();
    int beg = b * BIN_STRIDE;
    int count = bin_cursor[b];
    if (count > BIN_STRIDE) count = BIN_STRIDE;
    for (int i = beg + tid; i < beg + count; i += 256) {
        unsigned int ed = binned[i];
        atomicAdd(&lcnt[(ed >> 14) & 63], 1);
    }
    __syncthreads();
    if (tid < BIN_TGTS)
        dinv[b * BIN_TGTS + tid] = rsqrtf((float)(lcnt[tid] + 1));
}

// ---------------------------------------------------------------------------
// Fused aggregation + scores — EXACT round-3/4 proven body (67us, VGPR 40):
// 512 thr, 8 waves, phase-0 LDS scatter of this clip's half-bin, round-0
// 8-deep gather inner loop, dinv array. Round-5's chunk pipeline reverted.
// ---------------------------------------------------------------------------
__global__ __launch_bounds__(512) void k_agg_scores(
        const unsigned int* __restrict__ xwb,
        const unsigned int* __restrict__ binned,
        const int* __restrict__ bin_cursor,
        const float* __restrict__ dinv,
        const float* __restrict__ bias,
        float* __restrict__ out,      // Xo [NQ*DQ]
        float* __restrict__ mask) {   // [BQ*AQ*AQ]
    __shared__ float xs[AQ][DQ + 4];   // 33 KB; rows 1040B = 65x16B aligned
    __shared__ float sq[AQ];
    __shared__ float sc[AQ][AQ + 1];
    __shared__ float rmin[AQ], rmax[AQ];
    __shared__ unsigned short lbuck[AQ * DEG_STRIDE];  // 10 KB
    __shared__ int lcnt[AQ];

    int tid = threadIdx.x;
    int wave = tid >> 6;              // 0..7
    int lane = tid & 63;
    int bq = blockIdx.x;              // batch clip
    const uint2* xw2 = (const uint2*)xwb;

    // ---- phase 0: scatter this clip's edges into per-actor LDS lists ----
    if (tid < AQ) lcnt[tid] = 0;
    __syncthreads();
    {
        int b = bq >> 1;              // bin covering clips {2b, 2b+1}
        int beg = b * BIN_STRIDE;
        int count = bin_cursor[b];
        if (count > BIN_STRIDE) count = BIN_STRIDE;
        for (int i = beg + tid; i < beg + count; i += 512) {
            unsigned int ed = binned[i];
            if ((int)(ed >> 19) == bq) {          // target's clip == mine
                int a = (ed >> 14) & 31;
                int pos = atomicAdd(&lcnt[a], 1);
                if (pos < DEG_STRIDE)
                    lbuck[a * DEG_STRIDE + pos] = (unsigned short)(ed & 0x3FFFu);
            }
        }
    }
    __syncthreads();

    float4 bv = ((const float4*)bias)[lane];

    // ---- phase 1: gather 4 targets per wave (round-0 inner loop) ----
    #pragma unroll 1
    for (int i = 0; i < 4; i++) {
        int a = wave * 4 + i;         // actor 0..31
        int t = bq * AQ + a;
        float dt = dinv[t];
        float c0 = dt * dt;
        uint2 sp = xw2[(size_t)t * 64 + lane];
        float4 acc;
        acc.x = __uint_as_float(sp.x << 16) * c0;
        acc.y = __uint_as_float(sp.x & 0xFFFF0000u) * c0;
        acc.z = __uint_as_float(sp.y << 16) * c0;
        acc.w = __uint_as_float(sp.y & 0xFFFF0000u) * c0;

        int num = lcnt[a];
        if (num > DEG_STRIDE) num = DEG_STRIDE;
        for (int k0 = 0; k0 < num; k0 += 64) {
            int rem = num - k0;
            int n = rem < 64 ? rem : 64;
            int idx = k0 + (lane < n ? lane : 0);
            int e = (int)lbuck[a * DEG_STRIDE + idx];   // LDS, 2-way free
            float cl = (lane < n) ? dinv[e] * dt : 0.f;
            int n8 = (n + 7) & ~7;
            for (int j0 = 0; j0 < n8; j0 += 8) {
                #pragma unroll
                for (int jj = 0; jj < 8; jj++) {
                    int j = j0 + jj;
                    int s = __shfl(e, j);
                    float c = __shfl(cl, j);
                    uint2 p = xw2[(size_t)s * 64 + lane];
                    acc.x += __uint_as_float(p.x << 16) * c;
                    acc.y += __uint_as_float(p.x & 0xFFFF0000u) * c;
                    acc.z += __uint_as_float(p.y << 16) * c;
                    acc.w += __uint_as_float(p.y & 0xFFFF0000u) * c;
                }
            }
        }

        acc.x += bv.x; acc.y += bv.y; acc.z += bv.z; acc.w += bv.w;
        ((float4*)out)[(size_t)t * 64 + lane] = acc;
        *(float4*)&xs[a][lane * 4] = acc;
    }
    __syncthreads();

    // ---- phase 2: scores (identical math to round 0) ----
    if (tid < AQ) {
        const float4* xi = (const float4*)xs[tid];
        float s = 0.f;
        #pragma unroll 8
        for (int dd = 0; dd < DQ / 4; dd++) {
            float4 a = xi[dd];
            s += a.x * a.x + a.y * a.y + a.z * a.z + a.w * a.w;
        }
        sq[tid] = s;
    }
    __syncthreads();

    {
        int p0 = tid * 2;             // 2 pairs per thread (1024 pairs)
        int i = p0 >> 5;
        int j0 = p0 & 31;
        const float4* xi = (const float4*)xs[i];
        float g[2] = {0.f, 0.f};
        for (int dd = 0; dd < DQ / 4; dd += 8) {
            float4 ar[8];
            #pragma unroll
            for (int u = 0; u < 8; u++) ar[u] = xi[dd + u];
            #pragma unroll
            for (int q = 0; q < 2; q++) {
                const float4* xj = (const float4*)xs[j0 + q];
                float gq = 0.f;
                #pragma unroll
                for (int u = 0; u < 8; u++) {
                    float4 b = xj[dd + u];
                    gq += ar[u].x * b.x + ar[u].y * b.y +
                          ar[u].z * b.z + ar[u].w * b.w;
                }
                g[q] += gq;
            }
        }
        #pragma unroll
        for (int q = 0; q < 2; q++) {
            sc[i][j0 + q] = sq[i] - 2.f * g[q] + sq[j0 + q];
        }
    }
    __syncthreads();

    if (tid < AQ) {
        float mn = sc[tid][0], mx = sc[tid][0];
        for (int j = 1; j < AQ; j++) {
            float v = sc[tid][j];
            mn = fminf(mn, v);
            mx = fmaxf(mx, v);
        }
        rmin[tid] = mn;
        rmax[tid] = mx;
    }
    __syncthreads();

    {
        float* mb = mask + (size_t)bq * AQ * AQ;
        int p0 = tid * 2;
        int i = p0 >> 5, j0 = p0 & 31;
        float inv = 1.0f / (rmax[i] - rmin[i] + EPSF);
        float2 mv;
        mv.x = ((sc[i][j0 + 0] - rmin[i]) * inv > THR) ? 1.0f : 0.0f;
        mv.y = ((sc[i][j0 + 1] - rmin[i]) * inv > THR) ? 1.0f : 0.0f;
        ((float2*)mb)[tid] = mv;
    }
}

// ---------------------------------------------------------------------------
extern "C" void kernel_launch(void* const* d_in, const int* in_sizes, int n_in,
                              void* d_out, int out_size, void* d_ws, size_t ws_size,
                              hipStream_t stream) {
    const float* X    = (const float*)d_in[0];   // [B,A,D]
    const int*   ei   = (const int*)d_in[1];     // [2,E]
    const float* W    = (const float*)d_in[2];   // [D,D]
    const float* bias = (const float*)d_in[3];   // [D]
    float* out = (float*)d_out;                  // [N*D] Xo  ++  [B*A*A] mask

    char* ws = (char*)d_ws;
    unsigned short* xwb = (unsigned short*)ws;                              // 8 MB
    unsigned int* binned = (unsigned int*)(ws + (size_t)NQ * DQ * 2);       // 4.98 MB
    unsigned short* Wt = (unsigned short*)(binned + (size_t)NBINS * BIN_STRIDE); // 256 KB
    float* dinv = (float*)(Wt + 2 * DQ * DQ);                               // 64 KB
    int* bin_cursor = (int*)(dinv + NQ);                                    // 1 KB

    const int* src = ei;
    const int* tgt = ei + EQ;

    k_wt<<<256, 256, 0, stream>>>(W, Wt, bin_cursor);
    k_part<<<256, 256, 0, stream>>>(src, tgt, bin_cursor, binned);
    k_gemm<<<256, 256, 0, stream>>>(X, Wt, xwb);
    k_cnt<<<256, 256, 0, stream>>>(bin_cursor, binned, dinv);
    k_agg_scores<<<BQ, 512, 0, stream>>>((const unsigned int*)xwb, binned,
                                         bin_cursor, dinv, bias, out,
                                         out + (size_t)NQ * DQ);
}

// Round 7
// 172.799 us; speedup vs baseline: 1.2553x; 1.0367x over previous
//
#include <hip/hip_runtime.h>

// Problem constants (match reference)
#define BQ 512
#define AQ 32
#define DQ 256
#define NQ (BQ * AQ)      // 16384 nodes
#define EQ 1048576        // edges
#define THR 0.5f
#define EPSF 1e-5f
#define DEG_STRIDE 160    // per-target list cap; deg ~ Binom(E,1/N) mean 64, +12 sigma
#define BIN_TGTS 64       // targets per bin
#define NBINS (NQ / BIN_TGTS)          // 256
#define BIN_STRIDE 4864   // mean 4096 edges/bin, sigma ~64, +12 sigma

typedef __attribute__((ext_vector_type(8))) short bf16x8;
typedef __attribute__((ext_vector_type(4))) float f32x4;

// fp32 -> bf16 round-to-nearest-even (finite inputs)
__device__ __forceinline__ unsigned short f2bf(float f) {
    unsigned int u = __float_as_uint(f);
    return (unsigned short)((u + 0x7FFFu + ((u >> 16) & 1u)) >> 16);
}
__device__ __forceinline__ float bf2f(unsigned short h) {
    return __uint_as_float((unsigned int)h << 16);
}

// ---------------------------------------------------------------------------
// Dispatch 1 (round-0 skeleton, round-6 bodies):
//  blocks [0,256):    W [K,N] fp32 -> Wt hi/lo [N,K] bf16 split
//  blocks [256,512):  edge partition into 256 target-range bins
// bin_cursor pre-zeroed by hipMemsetAsync (must precede this dispatch).
// ---------------------------------------------------------------------------
__global__ __launch_bounds__(256) void k_wt_part(
        const float* __restrict__ W, unsigned short* __restrict__ Wt,
        const int* __restrict__ src, const int* __restrict__ tgt,
        int* __restrict__ bin_cursor, unsigned int* __restrict__ binned) {
    __shared__ int hist[NBINS];
    int tid = threadIdx.x;
    if (blockIdx.x < 256) {
        int idx = blockIdx.x * 256 + tid;       // covers DQ*DQ
        int n = idx >> 8;
        int k = idx & 255;
        float w = W[k * DQ + n];
        unsigned short h = f2bf(w);
        Wt[idx] = h;                            // hi plane
        Wt[DQ * DQ + idx] = f2bf(w - bf2f(h));  // lo plane
        return;
    }
    // ---- edge partition (EXACT round-6 body) ----
    hist[tid] = 0;
    __syncthreads();
    int base = (blockIdx.x - 256) * 4096;
    int t[16], s[16];
    #pragma unroll
    for (int i = 0; i < 16; i++) {
        int e = base + i * 256 + tid;
        t[i] = tgt[e];
        s[i] = src[e];
        atomicAdd(&hist[t[i] >> 6], 1);
    }
    __syncthreads();
    int mine = hist[tid];
    __syncthreads();
    hist[tid] = tid * BIN_STRIDE + atomicAdd(&bin_cursor[tid], mine);
    __syncthreads();
    #pragma unroll
    for (int i = 0; i < 16; i++) {
        int slot = atomicAdd(&hist[t[i] >> 6], 1);
        binned[slot] = ((unsigned int)t[i] << 14) | (unsigned int)s[i];
    }
}

// ---------------------------------------------------------------------------
// Dispatch 2:
//  blocks [0,256):    bf16x3 split MFMA GEMM with LDS-staged B (EXACT
//                     round-6 body; bit-identical output to rounds 0-6).
//  blocks [256,512):  per-bin degree count -> dinv (EXACT round-6 body;
//                     LDS aliased onto the GEMM staging buffer).
// ---------------------------------------------------------------------------
__global__ __launch_bounds__(256) void k_gemm_cnt(
        const float* __restrict__ Xp, const unsigned short* __restrict__ Wt,
        unsigned short* __restrict__ xwb,
        const int* __restrict__ bin_cursor, const unsigned int* __restrict__ binned,
        float* __restrict__ dinv) {
    __shared__ unsigned short bs[2][256 * 40];   // 40 KB (gemm); cnt aliases 256B
    int tid = threadIdx.x;
    if (blockIdx.x >= 256) {
        // ---- per-bin degree count ----
        int* lcnt = (int*)&bs[0][0];
        int b = blockIdx.x - 256;
        if (tid < BIN_TGTS) lcnt[tid] = 0;
        __syncthreads();
        int beg = b * BIN_STRIDE;
        int count = bin_cursor[b];
        if (count > BIN_STRIDE) count = BIN_STRIDE;
        for (int i = beg + tid; i < beg + count; i += 256) {
            unsigned int ed = binned[i];
            atomicAdd(&lcnt[(ed >> 14) & 63], 1);
        }
        __syncthreads();
        if (tid < BIN_TGTS)
            dinv[b * BIN_TGTS + tid] = rsqrtf((float)(lcnt[tid] + 1));
        return;
    }
    // ---- bf16x3 split MFMA GEMM, LDS-staged B (EXACT round-6 body) ----
    int wave = tid >> 6;
    int lane = tid & 63;
    int col = lane & 15;
    int quad = lane >> 4;
    int mbase = blockIdx.x * 64 + wave * 16;
    int m = mbase + col;

    const float* arow = Xp + (size_t)m * DQ;
    const unsigned short* Wlo = Wt + DQ * DQ;

    f32x4 acc[16];
    f32x4 zero = {0.f, 0.f, 0.f, 0.f};
    #pragma unroll
    for (int i = 0; i < 16; i++) acc[i] = zero;

    for (int k0 = 0; k0 < DQ; k0 += 32) {
        __syncthreads();              // previous slab fully consumed
        {
            const uint4* gh = (const uint4*)(Wt + tid * DQ + k0);   // 64B contig
            const uint4* gl = (const uint4*)(Wlo + tid * DQ + k0);
            uint4* lh = (uint4*)&bs[0][tid * 40];
            uint4* ll = (uint4*)&bs[1][tid * 40];
            #pragma unroll
            for (int u = 0; u < 4; u++) lh[u] = gh[u];
            #pragma unroll
            for (int u = 0; u < 4; u++) ll[u] = gl[u];
        }
        __syncthreads();

        int kq = k0 + quad * 8;
        float4 a0 = *(const float4*)(arow + kq);
        float4 a1 = *(const float4*)(arow + kq + 4);
        float av[8] = {a0.x, a0.y, a0.z, a0.w, a1.x, a1.y, a1.z, a1.w};
        bf16x8 ah, al;
        #pragma unroll
        for (int j = 0; j < 8; j++) {
            unsigned short h = f2bf(av[j]);
            ah[j] = (short)h;
            al[j] = (short)f2bf(av[j] - bf2f(h));
        }
        #pragma unroll
        for (int nt = 0; nt < 16; nt++) {
            int n = nt * 16 + col;
            bf16x8 bh = *(const bf16x8*)&bs[0][n * 40 + quad * 8];
            bf16x8 bl = *(const bf16x8*)&bs[1][n * 40 + quad * 8];
            acc[nt] = __builtin_amdgcn_mfma_f32_16x16x32_bf16(ah, bh, acc[nt], 0, 0, 0);
            acc[nt] = __builtin_amdgcn_mfma_f32_16x16x32_bf16(al, bh, acc[nt], 0, 0, 0);
            acc[nt] = __builtin_amdgcn_mfma_f32_16x16x32_bf16(ah, bl, acc[nt], 0, 0, 0);
        }
    }

    #pragma unroll
    for (int nt = 0; nt < 16; nt++) {
        #pragma unroll
        for (int r = 0; r < 4; r++) {
            xwb[(size_t)(mbase + quad * 4 + r) * DQ + nt * 16 + col] =
                f2bf(acc[nt][r]);
        }
    }
}

// ---------------------------------------------------------------------------
// Fused aggregation + scores — EXACT round-3/6 proven body (67us, VGPR 40):
// 512 thr, 8 waves, phase-0 LDS scatter of this clip's half-bin, round-0
// 8-deep gather inner loop, dinv array.
// ---------------------------------------------------------------------------
__global__ __launch_bounds__(512) void k_agg_scores(
        const unsigned int* __restrict__ xwb,
        const unsigned int* __restrict__ binned,
        const int* __restrict__ bin_cursor,
        const float* __restrict__ dinv,
        const float* __restrict__ bias,
        float* __restrict__ out,      // Xo [NQ*DQ]
        float* __restrict__ mask) {   // [BQ*AQ*AQ]
    __shared__ float xs[AQ][DQ + 4];   // 33 KB; rows 1040B = 65x16B aligned
    __shared__ float sq[AQ];
    __shared__ float sc[AQ][AQ + 1];
    __shared__ float rmin[AQ], rmax[AQ];
    __shared__ unsigned short lbuck[AQ * DEG_STRIDE];  // 10 KB
    __shared__ int lcnt[AQ];

    int tid = threadIdx.x;
    int wave = tid >> 6;              // 0..7
    int lane = tid & 63;
    int bq = blockIdx.x;              // batch clip
    const uint2* xw2 = (const uint2*)xwb;

    // ---- phase 0: scatter this clip's edges into per-actor LDS lists ----
    if (tid < AQ) lcnt[tid] = 0;
    __syncthreads();
    {
        int b = bq >> 1;              // bin covering clips {2b, 2b+1}
        int beg = b * BIN_STRIDE;
        int count = bin_cursor[b];
        if (count > BIN_STRIDE) count = BIN_STRIDE;
        for (int i = beg + tid; i < beg + count; i += 512) {
            unsigned int ed = binned[i];
            if ((int)(ed >> 19) == bq) {          // target's clip == mine
                int a = (ed >> 14) & 31;
                int pos = atomicAdd(&lcnt[a], 1);
                if (pos < DEG_STRIDE)
                    lbuck[a * DEG_STRIDE + pos] = (unsigned short)(ed & 0x3FFFu);
            }
        }
    }
    __syncthreads();

    float4 bv = ((const float4*)bias)[lane];

    // ---- phase 1: gather 4 targets per wave (round-0 inner loop) ----
    #pragma unroll 1
    for (int i = 0; i < 4; i++) {
        int a = wave * 4 + i;         // actor 0..31
        int t = bq * AQ + a;
        float dt = dinv[t];
        float c0 = dt * dt;
        uint2 sp = xw2[(size_t)t * 64 + lane];
        float4 acc;
        acc.x = __uint_as_float(sp.x << 16) * c0;
        acc.y = __uint_as_float(sp.x & 0xFFFF0000u) * c0;
        acc.z = __uint_as_float(sp.y << 16) * c0;
        acc.w = __uint_as_float(sp.y & 0xFFFF0000u) * c0;

        int num = lcnt[a];
        if (num > DEG_STRIDE) num = DEG_STRIDE;
        for (int k0 = 0; k0 < num; k0 += 64) {
            int rem = num - k0;
            int n = rem < 64 ? rem : 64;
            int idx = k0 + (lane < n ? lane : 0);
            int e = (int)lbuck[a * DEG_STRIDE + idx];   // LDS, 2-way free
            float cl = (lane < n) ? dinv[e] * dt : 0.f;
            int n8 = (n + 7) & ~7;
            for (int j0 = 0; j0 < n8; j0 += 8) {
                #pragma unroll
                for (int jj = 0; jj < 8; jj++) {
                    int j = j0 + jj;
                    int s = __shfl(e, j);
                    float c = __shfl(cl, j);
                    uint2 p = xw2[(size_t)s * 64 + lane];
                    acc.x += __uint_as_float(p.x << 16) * c;
                    acc.y += __uint_as_float(p.x & 0xFFFF0000u) * c;
                    acc.z += __uint_as_float(p.y << 16) * c;
                    acc.w += __uint_as_float(p.y & 0xFFFF0000u) * c;
                }
            }
        }

        acc.x += bv.x; acc.y += bv.y; acc.z += bv.z; acc.w += bv.w;
        ((float4*)out)[(size_t)t * 64 + lane] = acc;
        *(float4*)&xs[a][lane * 4] = acc;
    }
    __syncthreads();

    // ---- phase 2: scores (identical math to round 0) ----
    if (tid < AQ) {
        const float4* xi = (const float4*)xs[tid];
        float s = 0.f;
        #pragma unroll 8
        for (int dd = 0; dd < DQ / 4; dd++) {
            float4 a = xi[dd];
            s += a.x * a.x + a.y * a.y + a.z * a.z + a.w * a.w;
        }
        sq[tid] = s;
    }
    __syncthreads();

    {
        int p0 = tid * 2;             // 2 pairs per thread (1024 pairs)
        int i = p0 >> 5;
        int j0 = p0 & 31;
        const float4* xi = (const float4*)xs[i];
        float g[2] = {0.f, 0.f};
        for (int dd = 0; dd < DQ / 4; dd += 8) {
            float4 ar[8];
            #pragma unroll
            for (int u = 0; u < 8; u++) ar[u] = xi[dd + u];
            #pragma unroll
            for (int q = 0; q < 2; q++) {
                const float4* xj = (const float4*)xs[j0 + q];
                float gq = 0.f;
                #pragma unroll
                for (int u = 0; u < 8; u++) {
                    float4 b = xj[dd + u];
                    gq += ar[u].x * b.x + ar[u].y * b.y +
                          ar[u].z * b.z + ar[u].w * b.w;
                }
                g[q] += gq;
            }
        }
        #pragma unroll
        for (int q = 0; q < 2; q++) {
            sc[i][j0 + q] = sq[i] - 2.f * g[q] + sq[j0 + q];
        }
    }
    __syncthreads();

    if (tid < AQ) {
        float mn = sc[tid][0], mx = sc[tid][0];
        for (int j = 1; j < AQ; j++) {
            float v = sc[tid][j];
            mn = fminf(mn, v);
            mx = fmaxf(mx, v);
        }
        rmin[tid] = mn;
        rmax[tid] = mx;
    }
    __syncthreads();

    {
        float* mb = mask + (size_t)bq * AQ * AQ;
        int p0 = tid * 2;
        int i = p0 >> 5, j0 = p0 & 31;
        float inv = 1.0f / (rmax[i] - rmin[i] + EPSF);
        float2 mv;
        mv.x = ((sc[i][j0 + 0] - rmin[i]) * inv > THR) ? 1.0f : 0.0f;
        mv.y = ((sc[i][j0 + 1] - rmin[i]) * inv > THR) ? 1.0f : 0.0f;
        ((float2*)mb)[tid] = mv;
    }
}

// ---------------------------------------------------------------------------
extern "C" void kernel_launch(void* const* d_in, const int* in_sizes, int n_in,
                              void* d_out, int out_size, void* d_ws, size_t ws_size,
                              hipStream_t stream) {
    const float* X    = (const float*)d_in[0];   // [B,A,D]
    const int*   ei   = (const int*)d_in[1];     // [2,E]
    const float* W    = (const float*)d_in[2];   // [D,D]
    const float* bias = (const float*)d_in[3];   // [D]
    float* out = (float*)d_out;                  // [N*D] Xo  ++  [B*A*A] mask

    char* ws = (char*)d_ws;
    unsigned short* xwb = (unsigned short*)ws;                              // 8 MB
    unsigned int* binned = (unsigned int*)(ws + (size_t)NQ * DQ * 2);       // 4.98 MB
    unsigned short* Wt = (unsigned short*)(binned + (size_t)NBINS * BIN_STRIDE); // 512 KB
    float* dinv = (float*)(Wt + 2 * DQ * DQ);                               // 64 KB
    int* bin_cursor = (int*)(dinv + NQ);                                    // 1 KB

    const int* src = ei;
    const int* tgt = ei + EQ;

    hipMemsetAsync(bin_cursor, 0, NBINS * sizeof(int), stream);
    k_wt_part<<<512, 256, 0, stream>>>(W, Wt, src, tgt, bin_cursor, binned);
    k_gemm_cnt<<<512, 256, 0, stream>>>(X, Wt, xwb, bin_cursor, binned, dinv);
    k_agg_scores<<<BQ, 512, 0, stream>>>((const unsigned int*)xwb, binned,
                                         bin_cursor, dinv, bias, out,
                                         out + (size_t)NQ * DQ);
}